// Round 1
// baseline (161.267 us; speedup 1.0000x reference)
//
#include <hip/hip_runtime.h>
#include <hip/hip_bf16.h>
#include <stdint.h>

typedef float    f32x4  __attribute__((ext_vector_type(4)));
typedef float    f32x16 __attribute__((ext_vector_type(16)));
typedef short    s16x8  __attribute__((ext_vector_type(8)));
typedef uint32_t u32x4  __attribute__((ext_vector_type(4)));

#define NB 8
#define NT 2048
#define NC 768
#define NH 64

__device__ __forceinline__ uint32_t f2bf1(float f) {
  union { float f; uint32_t u; } v; v.f = f;
  uint32_t u = v.u;
  return (u + 0x7fffu + ((u >> 16) & 1u)) >> 16;   // RNE
}
__device__ __forceinline__ uint32_t packbf2(float lo, float hi) {
  return f2bf1(lo) | (f2bf1(hi) << 16);
}

// ---------------- kernel 1: weights fp32 -> fused bf16 [192][768] (q:0-63,k:64-127,v:128-191)
__global__ __launch_bounds__(256) void wconv_kernel(
    const float* __restrict__ Wk, const float* __restrict__ Wq,
    const float* __restrict__ Wv, short* __restrict__ Wb)
{
  int idx = blockIdx.x * 256 + threadIdx.x;
  if (idx >= 192 * 768) return;
  int n = idx / 768;
  float v;
  if (n < 64)       v = Wq[idx];
  else if (n < 128) v = Wk[idx - 64 * 768];
  else              v = Wv[idx - 128 * 768];
  Wb[idx] = (short)f2bf1(v);
}

// ---------------- kernel 2: projection GEMM -> qb,kb [tok][64] bf16; v transposed [B][64][T] bf16
// block = 128 threads (2 waves), 32 tokens/block, each wave owns 3 N-tiles of 32.
__global__ __launch_bounds__(128) void proj_kernel(
    const float* __restrict__ x, const short* __restrict__ Wb,
    short* __restrict__ qb, short* __restrict__ kb, short* __restrict__ vTb)
{
  __shared__ short ldsX[32 * 64];   // [32 tok][64 k] bf16 (4KB), reused as [64 h][32 tok] in epilogue

  const int tid  = threadIdx.x;
  const int lane = tid & 63;
  const int wave = tid >> 6;
  const int col  = lane & 31;
  const int half = lane >> 5;
  const int t0   = blockIdx.x * 32;

  f32x16 acc[3];
#pragma unroll
  for (int j = 0; j < 3; ++j)
#pragma unroll
    for (int e = 0; e < 16; ++e) acc[j][e] = 0.f;

  // staging: 128 chunks of 16 floats, one per thread
  const int sr = tid >> 2;            // token row 0..31
  const int sf = (tid & 3) * 16;      // float offset in row
  const float* xsrc = x + (size_t)(t0 + sr) * NC + sf;

  f32x4 st[4];
#pragma unroll
  for (int u = 0; u < 4; ++u) st[u] = *(const f32x4*)(xsrc + u * 4);

  for (int k0 = 0; k0 < NC; k0 += 64) {
    __syncthreads();
    {
      uint32_t pw[8];
#pragma unroll
      for (int u = 0; u < 4; ++u) {
        pw[2 * u]     = packbf2(st[u][0], st[u][1]);
        pw[2 * u + 1] = packbf2(st[u][2], st[u][3]);
      }
      *(u32x4*)&ldsX[sr * 64 + sf]     = (u32x4){pw[0], pw[1], pw[2], pw[3]};
      *(u32x4*)&ldsX[sr * 64 + sf + 8] = (u32x4){pw[4], pw[5], pw[6], pw[7]};
    }
    __syncthreads();
    if (k0 + 64 < NC) {
#pragma unroll
      for (int u = 0; u < 4; ++u) st[u] = *(const f32x4*)(xsrc + k0 + 64 + u * 4);
    }
#pragma unroll
    for (int ks = 0; ks < 4; ++ks) {
      s16x8 af = *(const s16x8*)&ldsX[col * 64 + ks * 16 + half * 8];
#pragma unroll
      for (int j = 0; j < 3; ++j) {
        int n = (wave * 3 + j) * 32 + col;
        s16x8 bf = *(const s16x8*)&Wb[(size_t)n * NC + k0 + ks * 16 + half * 8];
        acc[j] = __builtin_amdgcn_mfma_f32_32x32x16_bf16(af, bf, acc[j], 0, 0, 0);
      }
    }
  }

  const int b  = t0 >> 11;
  const int tl = t0 & (NT - 1);

  // q / k tiles: direct bf16 stores [tok][64]
#pragma unroll
  for (int j = 0; j < 3; ++j) {
    int nb = (wave * 3 + j) * 32;
    if (nb < 128) {
      short* dst = (nb < 64) ? qb : kb;
      int hb = (nb & 63) + col;
#pragma unroll
      for (int r = 0; r < 16; ++r) {
        int rd = (r & 3) + 8 * (r >> 2) + 4 * half;   // token row in tile
        dst[(size_t)(t0 + rd) * NH + hb] = (short)f2bf1(acc[j][r]);
      }
    }
  }
  // v tiles: transpose through LDS -> vTb [B][64][T]
  __syncthreads();
#pragma unroll
  for (int j = 0; j < 3; ++j) {
    int nb = (wave * 3 + j) * 32;
    if (nb >= 128) {
      int h0 = (nb - 128) + col;
#pragma unroll
      for (int r = 0; r < 16; ++r) {
        int rd = (r & 3) + 8 * (r >> 2) + 4 * half;
        ldsX[h0 * 32 + rd] = (short)f2bf1(acc[j][r]);   // [h][tok]
      }
    }
  }
  __syncthreads();
#pragma unroll
  for (int i = 0; i < 2; ++i) {
    int c = i * 128 + tid;          // 256 chunks of 16B
    int h = c >> 2;
    int off = (c & 3) * 8;
    *(s16x8*)&vTb[(size_t)(b * NH + h) * NT + tl + off] = *(const s16x8*)&ldsX[h * 32 + off];
  }
}

// ---------------- kernel 3: flash attention, S^T trick. 1 wave = 32 queries, 32-key tiles.
__global__ __launch_bounds__(64) void attn_kernel(
    const short* __restrict__ qb, const short* __restrict__ kb,
    const short* __restrict__ vTb, float* __restrict__ out)
{
  __shared__ short ldsK[32 * 64];   // [32 key][64 h]
  __shared__ short ldsV[64 * 32];   // [64 h][32 key]
  __shared__ float ldsO[32 * 64];   // epilogue transpose

  const int lane = threadIdx.x;
  const int col  = lane & 31;
  const int half = lane >> 5;
  const int b    = blockIdx.x >> 6;
  int qt = blockIdx.x & 63;
  if (blockIdx.x & 256) qt = 63 - qt;   // pair heavy+light q-tiles on the same CU
  const int q0 = qt * 32;

  // persistent Q fragments (B-operand of S^T = K * Q^T)
  s16x8 qf[4];
  {
    const short* qptr = qb + (size_t)(b * NT + q0 + col) * NH + half * 8;
#pragma unroll
    for (int ks = 0; ks < 4; ++ks) qf[ks] = *(const s16x8*)(qptr + ks * 16);
  }

  f32x16 oacc[2];
#pragma unroll
  for (int t = 0; t < 2; ++t)
#pragma unroll
    for (int e = 0; e < 16; ++e) oacc[t][e] = 0.f;

  float m = -1e30f, l = 0.f;
  const int nIter = qt + 1;

  const short* kbase = kb  + (size_t)(b * NT) * NH;
  const short* vbase = vTb + (size_t)(b * NH) * NT;

  f32x4 rK[4], rV[4];
  auto load_tiles = [&](int k0) {
#pragma unroll
    for (int i = 0; i < 4; ++i) {
      rK[i] = *(const f32x4*)(kbase + k0 * 64 + (lane + 64 * i) * 8);
      int h = (lane >> 2) + 16 * i;
      rV[i] = *(const f32x4*)(vbase + (size_t)h * NT + k0 + (lane & 3) * 8);
    }
  };
  load_tiles(0);

  for (int it = 0; it < nIter; ++it) {
    __syncthreads();
#pragma unroll
    for (int i = 0; i < 4; ++i) {
      *(f32x4*)&ldsK[(lane + 64 * i) * 8] = rK[i];
      int h = (lane >> 2) + 16 * i;
      *(f32x4*)&ldsV[h * 32 + (lane & 3) * 8] = rV[i];
    }
    __syncthreads();
    if (it + 1 < nIter) load_tiles((it + 1) * 32);

    // S^T tile [32 key][32 query]: A = K rows, B = Q rows
    f32x16 s;
#pragma unroll
    for (int e = 0; e < 16; ++e) s[e] = 0.f;
#pragma unroll
    for (int ks = 0; ks < 4; ++ks) {
      s16x8 kf = *(const s16x8*)&ldsK[col * 64 + ks * 16 + half * 8];
      s = __builtin_amdgcn_mfma_f32_32x32x16_bf16(kf, qf[ks], s, 0, 0, 0);
    }
    if (it == nIter - 1) {            // diagonal tile: mask key > query
#pragma unroll
      for (int r = 0; r < 16; ++r) {
        int rd = (r & 3) + 8 * (r >> 2) + 4 * half;
        if (rd > col) s[r] = -1e30f;
      }
    }
    // online softmax: stats are per-lane (query = col); one shfl to merge halves
    float vmax = s[0];
#pragma unroll
    for (int r = 1; r < 16; ++r) vmax = fmaxf(vmax, s[r]);
    vmax = fmaxf(vmax, __shfl_xor(vmax, 32));
    float mn    = fmaxf(m, vmax);
    float alpha = __expf(m - mn);
    float p[16];
    float rs = 0.f;
#pragma unroll
    for (int r = 0; r < 16; ++r) { p[r] = __expf(s[r] - mn); rs += p[r]; }
    rs += __shfl_xor(rs, 32);
    l = l * alpha + rs;
    m = mn;
#pragma unroll
    for (int t = 0; t < 2; ++t)
#pragma unroll
      for (int e = 0; e < 16; ++e) oacc[t][e] *= alpha;

    // P^T (C-layout) -> B-operand frags via one half-swap shuffle per word pair
    uint32_t pw[8];
#pragma unroll
    for (int i = 0; i < 8; ++i) pw[i] = packbf2(p[2 * i], p[2 * i + 1]);
#pragma unroll
    for (int kc = 0; kc < 2; ++kc) {
      uint32_t s0 = half ? pw[4 * kc]     : pw[4 * kc + 2];
      uint32_t s1 = half ? pw[4 * kc + 1] : pw[4 * kc + 3];
      uint32_t r0 = __shfl_xor(s0, 32);
      uint32_t r1 = __shfl_xor(s1, 32);
      uint32_t w0 = half ? r0 : pw[4 * kc];
      uint32_t w1 = half ? r1 : pw[4 * kc + 1];
      uint32_t w2 = half ? pw[4 * kc + 2] : r0;
      uint32_t w3 = half ? pw[4 * kc + 3] : r1;
      union { u32x4 u; s16x8 v; } pf;
      pf.u = (u32x4){w0, w1, w2, w3};
#pragma unroll
      for (int ht = 0; ht < 2; ++ht) {
        s16x8 vf = *(const s16x8*)&ldsV[(ht * 32 + col) * 32 + kc * 16 + half * 8];
        oacc[ht] = __builtin_amdgcn_mfma_f32_32x32x16_bf16(vf, pf.v, oacc[ht], 0, 0, 0);
      }
    }
  }

  // epilogue: O^T -> [query][h] through LDS, coalesced fp32 store
  float inv = 1.0f / l;
  __syncthreads();
#pragma unroll
  for (int ht = 0; ht < 2; ++ht)
#pragma unroll
    for (int r = 0; r < 16; ++r) {
      int rd = (r & 3) + 8 * (r >> 2) + 4 * half;
      ldsO[col * 64 + ht * 32 + rd] = oacc[ht][r] * inv;
    }
  __syncthreads();
  float* obase = out + (size_t)(b * NT + q0) * NH;
#pragma unroll
  for (int i = 0; i < 8; ++i) {
    int c = i * 64 + lane;
    int q = c >> 4, off = (c & 15) * 4;
    *(f32x4*)(obase + q * NH + off) = *(const f32x4*)&ldsO[q * 64 + off];
  }
}

extern "C" void kernel_launch(void* const* d_in, const int* in_sizes, int n_in,
                              void* d_out, int out_size, void* d_ws, size_t ws_size,
                              hipStream_t stream) {
  const float* x  = (const float*)d_in[0];
  const float* Wk = (const float*)d_in[1];
  const float* Wq = (const float*)d_in[2];
  const float* Wv = (const float*)d_in[3];
  float* out = (float*)d_out;

  char* ws = (char*)d_ws;
  short* Wb  = (short*)(ws);                          // 294912 B
  short* qb  = (short*)(ws + 524288);                 // 2 MB
  short* kb  = (short*)(ws + 524288 + 2097152);       // 2 MB
  short* vTb = (short*)(ws + 524288 + 2 * 2097152);   // 2 MB

  hipLaunchKernelGGL(wconv_kernel, dim3(576), dim3(256), 0, stream, Wk, Wq, Wv, Wb);
  hipLaunchKernelGGL(proj_kernel,  dim3(512), dim3(128), 0, stream, x, Wb, qb, kb, vTb);
  hipLaunchKernelGGL(attn_kernel,  dim3(512), dim3(64),  0, stream, qb, kb, vTb, out);
}

// Round 2
// 132.673 us; speedup vs baseline: 1.2155x; 1.2155x over previous
//
#include <hip/hip_runtime.h>
#include <hip/hip_bf16.h>
#include <stdint.h>

typedef float    f32x4  __attribute__((ext_vector_type(4)));
typedef float    f32x16 __attribute__((ext_vector_type(16)));
typedef short    s16x8  __attribute__((ext_vector_type(8)));
typedef uint32_t u32x4  __attribute__((ext_vector_type(4)));

#define NB 8
#define NT 2048
#define NC 768
#define NH 64

__device__ __forceinline__ uint32_t f2bf1(float f) {
  union { float f; uint32_t u; } v; v.f = f;
  uint32_t u = v.u;
  return (u + 0x7fffu + ((u >> 16) & 1u)) >> 16;   // RNE
}
__device__ __forceinline__ uint32_t packbf2(float lo, float hi) {
  return f2bf1(lo) | (f2bf1(hi) << 16);
}

// ---------------- kernel 1: weights fp32 -> fused bf16 [192][768] (q:0-63,k:64-127,v:128-191)
__global__ __launch_bounds__(256) void wconv_kernel(
    const float* __restrict__ Wk, const float* __restrict__ Wq,
    const float* __restrict__ Wv, short* __restrict__ Wb)
{
  int idx = blockIdx.x * 256 + threadIdx.x;
  if (idx >= 192 * 768) return;
  int n = idx / 768;
  float v;
  if (n < 64)       v = Wq[idx];
  else if (n < 128) v = Wk[idx - 64 * 768];
  else              v = Wv[idx - 128 * 768];
  Wb[idx] = (short)f2bf1(v);
}

// ---------------- kernel 2: projection GEMM, split-K in-block.
// block = 256 thr (4 waves): wave w -> K-half kh=w>>1, N-half nh=w&1 (3 N-tiles of 32).
// 32 tokens/block. fp32 merge of K-halves through LDS, then bf16 stores (v transposed).
__global__ __launch_bounds__(256) void proj_kernel(
    const float* __restrict__ x, const short* __restrict__ Wb,
    short* __restrict__ qb, short* __restrict__ kb, short* __restrict__ vTb)
{
  __shared__ char smem[8192 + 24576];
  short* ldsX   = (short*)smem;            // [2][32][64] bf16, 8 KB
  float* ldsAcc = (float*)(smem + 8192);   // [32][192] fp32, 24 KB
  short* ldsV   = (short*)smem;            // [64][32] bf16 (reused after loop)

  const int tid  = threadIdx.x;
  const int lane = tid & 63;
  const int w    = tid >> 6;
  const int kh   = w >> 1;
  const int nh   = w & 1;
  const int col  = lane & 31;
  const int half = lane >> 5;
  const int t0   = blockIdx.x * 32;

  f32x16 acc[3];
#pragma unroll
  for (int j = 0; j < 3; ++j)
#pragma unroll
    for (int e = 0; e < 16; ++e) acc[j][e] = 0.f;

  // staging: threads 0-127 stage K-half 0, 128-255 stage K-half 1 (32 tok x 64 cols each)
  const int sg  = tid & 127;
  const int skh = tid >> 7;
  const int sr  = sg >> 2;
  const int sf  = (sg & 3) * 16;
  const float* xsrc = x + (size_t)(t0 + sr) * NC + skh * 384 + sf;
  short* ldst = ldsX + skh * 2048 + sr * 64 + sf;

  f32x4 st[4];
#pragma unroll
  for (int u = 0; u < 4; ++u) st[u] = *(const f32x4*)(xsrc + u * 4);

  const short* wbase = Wb + kh * 384 + half * 8;

  for (int s = 0; s < 6; ++s) {
    __syncthreads();
    {
      uint32_t pw[8];
#pragma unroll
      for (int u = 0; u < 4; ++u) {
        pw[2 * u]     = packbf2(st[u][0], st[u][1]);
        pw[2 * u + 1] = packbf2(st[u][2], st[u][3]);
      }
      *(u32x4*)ldst       = (u32x4){pw[0], pw[1], pw[2], pw[3]};
      *(u32x4*)(ldst + 8) = (u32x4){pw[4], pw[5], pw[6], pw[7]};
    }
    __syncthreads();
    if (s < 5) {
#pragma unroll
      for (int u = 0; u < 4; ++u) st[u] = *(const f32x4*)(xsrc + (s + 1) * 64 + u * 4);
    }
#pragma unroll
    for (int ks = 0; ks < 4; ++ks) {
      s16x8 af = *(const s16x8*)&ldsX[kh * 2048 + col * 64 + ks * 16 + half * 8];
#pragma unroll
      for (int j = 0; j < 3; ++j) {
        int n = (nh * 3 + j) * 32 + col;
        s16x8 bf = *(const s16x8*)(wbase + (size_t)n * NC + s * 64 + ks * 16);
        acc[j] = __builtin_amdgcn_mfma_f32_32x32x16_bf16(af, bf, acc[j], 0, 0, 0);
      }
    }
  }

  // merge K-halves: kh0 writes fp32 partials, kh1 adds + stores
  if (kh == 0) {
#pragma unroll
    for (int j = 0; j < 3; ++j)
#pragma unroll
      for (int r = 0; r < 16; ++r) {
        int rd = (r & 3) + 8 * (r >> 2) + 4 * half;
        ldsAcc[rd * 192 + (nh * 3 + j) * 32 + col] = acc[j][r];
      }
  }
  __syncthreads();
  const int b  = t0 >> 11;
  const int tl = t0 & (NT - 1);
  if (kh == 1) {
#pragma unroll
    for (int j = 0; j < 3; ++j) {
      int nb = (nh * 3 + j) * 32;
#pragma unroll
      for (int r = 0; r < 16; ++r) {
        int rd = (r & 3) + 8 * (r >> 2) + 4 * half;
        float sum = acc[j][r] + ldsAcc[rd * 192 + nb + col];
        if (nb < 128) {
          short* dst = (nb < 64) ? qb : kb;
          dst[(size_t)(t0 + rd) * NH + (nb & 63) + col] = (short)f2bf1(sum);
        } else {
          ldsV[(nb - 128 + col) * 32 + rd] = (short)f2bf1(sum);
        }
      }
    }
  }
  __syncthreads();
  {
    int h = tid >> 2, off = (tid & 3) * 8;
    *(s16x8*)&vTb[(size_t)(b * NH + h) * NT + tl + off] = *(const s16x8*)&ldsV[h * 32 + off];
  }
}

// ---------------- kernel 3: flash attention, S^T trick, split-K across 4 waves.
// block = 256 thr (4 waves), one 32-query tile; wave w owns key-tile range [w*nT/4,(w+1)*nT/4).
// K/V fragments loaded directly from global (L2-resident) -> no barriers in the loop.
__global__ __launch_bounds__(256) void attn_kernel(
    const short* __restrict__ qb, const short* __restrict__ kb,
    const short* __restrict__ vTb, float* __restrict__ out)
{
  __shared__ float ldsO[4][32][65];   // per-wave O^T partials, padded (+1 breaks 256B stride)
  __shared__ float ldsM[4][32];
  __shared__ float ldsL[4][32];

  const int tid  = threadIdx.x;
  const int lane = tid & 63;
  const int w    = tid >> 6;
  const int col  = lane & 31;
  const int half = lane >> 5;
  const int b    = blockIdx.x >> 6;
  int qt = blockIdx.x & 63;
  if (blockIdx.x & 256) qt = 63 - qt;   // pair heavy+light q-tiles per CU
  const int q0 = qt * 32;
  const int nT = qt + 1;
  const int tBeg = (w * nT) >> 2;
  const int tEnd = ((w + 1) * nT) >> 2;

  // persistent Q fragments (B-operand of S^T = K * Q^T)
  s16x8 qf[4];
  {
    const short* qptr = qb + (size_t)(b * NT + q0 + col) * NH + half * 8;
#pragma unroll
    for (int ks = 0; ks < 4; ++ks) qf[ks] = *(const s16x8*)(qptr + ks * 16);
  }

  const short* kbase = kb  + (size_t)(b * NT + col) * NH + half * 8;
  const short* vbase = vTb + (size_t)(b * NH + col) * NT + half * 8;

  f32x16 oacc[2];
#pragma unroll
  for (int t = 0; t < 2; ++t)
#pragma unroll
    for (int e = 0; e < 16; ++e) oacc[t][e] = 0.f;

  float m = -1e30f, l = 0.f;

  s16x8 rk[4], rv[4];
  auto prefetch = [&](int t) {
#pragma unroll
    for (int ks = 0; ks < 4; ++ks)
      rk[ks] = *(const s16x8*)(kbase + (size_t)t * 32 * NH + ks * 16);
#pragma unroll
    for (int i = 0; i < 4; ++i)
      rv[i] = *(const s16x8*)(vbase + (size_t)(i >> 1) * 32 * NT + t * 32 + (i & 1) * 16);
  };
  if (tBeg < tEnd) prefetch(tBeg);

  for (int t = tBeg; t < tEnd; ++t) {
    s16x8 ck[4] = {rk[0], rk[1], rk[2], rk[3]};
    s16x8 cv[4] = {rv[0], rv[1], rv[2], rv[3]};
    if (t + 1 < tEnd) prefetch(t + 1);

    // S^T tile [32 key][32 query]
    f32x16 s;
#pragma unroll
    for (int e = 0; e < 16; ++e) s[e] = 0.f;
#pragma unroll
    for (int ks = 0; ks < 4; ++ks)
      s = __builtin_amdgcn_mfma_f32_32x32x16_bf16(ck[ks], qf[ks], s, 0, 0, 0);

    if (t == nT - 1) {                 // diagonal tile: mask key > query
#pragma unroll
      for (int r = 0; r < 16; ++r) {
        int rd = (r & 3) + 8 * (r >> 2) + 4 * half;
        if (rd > col) s[r] = -1e30f;
      }
    }
    // online softmax (query = col lives per-lane; one shfl merges halves)
    float vmax = s[0];
#pragma unroll
    for (int r = 1; r < 16; ++r) vmax = fmaxf(vmax, s[r]);
    vmax = fmaxf(vmax, __shfl_xor(vmax, 32));
    float mn    = fmaxf(m, vmax);
    float alpha = __expf(m - mn);
    float p[16];
    float rs = 0.f;
#pragma unroll
    for (int r = 0; r < 16; ++r) { p[r] = __expf(s[r] - mn); rs += p[r]; }
    rs += __shfl_xor(rs, 32);
    l = l * alpha + rs;
    m = mn;
#pragma unroll
    for (int t2 = 0; t2 < 2; ++t2)
#pragma unroll
      for (int e = 0; e < 16; ++e) oacc[t2][e] *= alpha;

    // P^T (C-layout) -> B-operand frags via one half-swap shuffle per word pair
    uint32_t pw[8];
#pragma unroll
    for (int i = 0; i < 8; ++i) pw[i] = packbf2(p[2 * i], p[2 * i + 1]);
#pragma unroll
    for (int kc = 0; kc < 2; ++kc) {
      uint32_t s0 = half ? pw[4 * kc]     : pw[4 * kc + 2];
      uint32_t s1 = half ? pw[4 * kc + 1] : pw[4 * kc + 3];
      uint32_t r0 = __shfl_xor(s0, 32);
      uint32_t r1 = __shfl_xor(s1, 32);
      uint32_t w0 = half ? r0 : pw[4 * kc];
      uint32_t w1 = half ? r1 : pw[4 * kc + 1];
      uint32_t w2 = half ? pw[4 * kc + 2] : r0;
      uint32_t w3 = half ? pw[4 * kc + 3] : r1;
      union { u32x4 u; s16x8 v; } pf;
      pf.u = (u32x4){w0, w1, w2, w3};
#pragma unroll
      for (int ht = 0; ht < 2; ++ht)
        oacc[ht] = __builtin_amdgcn_mfma_f32_32x32x16_bf16(cv[ht * 2 + kc], pf.v, oacc[ht], 0, 0, 0);
    }
  }

  // merge partials across the 4 waves
  if (half == 0) { ldsM[w][col] = m; ldsL[w][col] = l; }
#pragma unroll
  for (int ht = 0; ht < 2; ++ht)
#pragma unroll
    for (int r = 0; r < 16; ++r) {
      int rd = (r & 3) + 8 * (r >> 2) + 4 * half;
      ldsO[w][col][ht * 32 + rd] = oacc[ht][r];
    }
  __syncthreads();

  const int q  = tid >> 3;
  const int h0 = (tid & 7) * 8;
  float mv[4], lv[4];
#pragma unroll
  for (int i = 0; i < 4; ++i) { mv[i] = ldsM[i][q]; lv[i] = ldsL[i][q]; }
  float M = fmaxf(fmaxf(mv[0], mv[1]), fmaxf(mv[2], mv[3]));
  float cf[4], L = 0.f;
#pragma unroll
  for (int i = 0; i < 4; ++i) { cf[i] = __expf(mv[i] - M); L += cf[i] * lv[i]; }
  float inv = 1.0f / L;
  float o[8];
#pragma unroll
  for (int j = 0; j < 8; ++j) {
    float a = 0.f;
#pragma unroll
    for (int i = 0; i < 4; ++i) a += cf[i] * ldsO[i][q][h0 + j];
    o[j] = a * inv;
  }
  float* obase = out + (size_t)(b * NT + q0 + q) * NH + h0;
  *(f32x4*)obase       = (f32x4){o[0], o[1], o[2], o[3]};
  *(f32x4*)(obase + 4) = (f32x4){o[4], o[5], o[6], o[7]};
}

extern "C" void kernel_launch(void* const* d_in, const int* in_sizes, int n_in,
                              void* d_out, int out_size, void* d_ws, size_t ws_size,
                              hipStream_t stream) {
  const float* x  = (const float*)d_in[0];
  const float* Wk = (const float*)d_in[1];
  const float* Wq = (const float*)d_in[2];
  const float* Wv = (const float*)d_in[3];
  float* out = (float*)d_out;

  char* ws = (char*)d_ws;
  short* Wb  = (short*)(ws);                          // 294912 B
  short* qb  = (short*)(ws + 524288);                 // 2 MB
  short* kb  = (short*)(ws + 524288 + 2097152);       // 2 MB
  short* vTb = (short*)(ws + 524288 + 2 * 2097152);   // 2 MB

  hipLaunchKernelGGL(wconv_kernel, dim3(576), dim3(256), 0, stream, Wk, Wq, Wv, Wb);
  hipLaunchKernelGGL(proj_kernel,  dim3(512), dim3(256), 0, stream, x, Wb, qb, kb, vTb);
  hipLaunchKernelGGL(attn_kernel,  dim3(512), dim3(256), 0, stream, qb, kb, vTb, out);
}